// Round 6
// baseline (95.309 us; speedup 1.0000x reference)
//
#include <hip/hip_runtime.h>

// B=2, Hi=Wi=64, Di=32, C=16, F=8, strides (2,2,2), k=3x3x3, Ho=Wo=128, Do=64.
constexpr int Bc  = 2;
constexpr int HiC = 64, WiC = 64, DiC = 32;
constexpr int Cc  = 16, Fc  = 8;
constexpr int HoC = 128, WoC = 128, DoC = 64;

constexpr int SLAB_SHORTS = DiC * Cc;                  // 512 shorts = 1 KiB slab
constexpr int NSLAB       = 10;                        // 2 hi rows x 5 wi cols
constexpr int ZOFF        = NSLAB * SLAB_SHORTS * 2;   // LDS byte offset of zero block

typedef __attribute__((ext_vector_type(8))) short short8;   // 8 bf16 = A/B frag
typedef __attribute__((ext_vector_type(4))) float f32x4;    // MFMA accumulator

__device__ alignas(16) const float FZERO[8] = {0, 0, 0, 0, 0, 0, 0, 0};

__device__ __forceinline__ unsigned pk2(float x, float y) {   // RNE f32x2 -> bf16x2
    unsigned ux = __float_as_uint(x), uy = __float_as_uint(y);
    ux += ((ux >> 16) & 1u) + 0x7FFFu;
    uy += ((uy >> 16) & 1u) + 0x7FFFu;
    return (ux >> 16) | (uy & 0xFFFF0000u);
}
__device__ __forceinline__ short8 pack8(float4 a, float4 b) {
    union { unsigned u[4]; short8 s; } r;
    r.u[0] = pk2(a.x, a.y); r.u[1] = pk2(a.z, a.w);
    r.u[2] = pk2(b.x, b.y); r.u[3] = pk2(b.z, b.w);
    return r.s;
}

// Wave = 4 same-parity columns of one output row. Per column: out[do,f] over
// (pos,kd,c) packed in MFMA K=32. E rows (bp+do+1 even): per position, k-halves
// = kd0/kd2. O rows (kd=1): two positions per MFMA. A: A[m=lane&15][k=quad*8+j];
// B: B[k][n=lane&15]; C/D: col=lane&15, row=quad*4+reg. (round-7/8 verified)
// Round 14: r5 counters showed sconv = 45 us, stall-bound (MFMA 2.7%, VALU 13%,
// HBM 20%, occ 33%). Halve per-wave serial chain + double wave count:
// block = 8 wo x 2 ho (grid 2048); the 4 waves split by (wo-parity, ho-parity),
// each wave makes ONE doCols call (4 columns) instead of two. 10-slab staging,
// LDS 18.4 KiB -> 8 blocks/CU, __launch_bounds__(256,8) for 32 waves/CU.
template<int CLS>
__device__ __forceinline__ void doCols(const short* __restrict__ slabs,
                                       const int*   __restrict__ bp,
                                       const float* __restrict__ kern,
                                       float*       __restrict__ out,
                                       float*       __restrict__ ldsw,
                                       int b, int ho, int wo0, int wi0, int lane) {
    constexpr int NP = (CLS == 0) ? 1 : ((CLS == 3) ? 4 : 2);
    constexpr int OP = (NP + 1) / 2;
    constexpr int KH[4][4] = {{1,0,0,0},{1,1,0,0},{0,2,0,0},{0,0,2,2}};
    constexpr int KW[4][4] = {{1,0,0,0},{0,2,0,0},{1,1,0,0},{0,2,0,2}};

    const int quad = lane >> 4, n = lane & 15;
    const int half = quad >> 1, chalf = quad & 1;   // k-half, channel-half
    const int chalfB = chalf * 16;                  // byte offset within di row

    // ---- B fragments in-register from f32 kern (amortized over 4 columns) ----
    short8 bE[NP], bO[OP];
    #pragma unroll
    for (int p = 0; p < NP; ++p) {
        const int kp = KH[CLS][p] * 3 + KW[CLS][p];
        const float* wp = (n < Fc)
            ? kern + (kp * 3 + 2 * half) * 128 + n * 16 + chalf * 8 : FZERO;
        bE[p] = pack8(*(const float4*)wp, *(const float4*)(wp + 4));
    }
    #pragma unroll
    for (int pp = 0; pp < OP; ++pp) {
        const int  PA   = (2 * pp < NP) ? 2 * pp : 0;
        const bool hasB = (2 * pp + 1) < NP;
        const int  PB   = hasB ? (2 * pp + 1) : 0;
        const int kpa = KH[CLS][PA] * 3 + KW[CLS][PA];
        const int kpb = KH[CLS][PB] * 3 + KW[CLS][PB];
        const int kp  = half ? kpb : kpa;
        const bool v  = (n < Fc) && (!half || hasB);
        const float* wp = v ? kern + (kp * 3 + 1) * 128 + n * 16 + chalf * 8 : FZERO;
        bO[pp] = pack8(*(const float4*)wp, *(const float4*)(wp + 4));
    }

    // ---- phase 1: ALL scalar loads for all 4 columns ----
    int colx[4], bpcol[4], bpgr[4][NP], pxo[4][NP]; bool pvs[4][NP];
    #pragma unroll
    for (int cc = 0; cc < 4; ++cc) {
        const int wo = wo0 + 2 * cc;
        colx[cc]  = __builtin_amdgcn_readfirstlane((b * HoC + ho) * WoC + wo);
        bpcol[cc] = bp[colx[cc]];                    // uniform -> s_load
        #pragma unroll
        for (int p = 0; p < NP; ++p) {
            const int kh = KH[CLS][p], kw = KW[CLS][p];
            int hi = (ho + 1 - kh) >> 1; hi = hi > HiC - 1 ? HiC - 1 : hi;
            int wi = (wo + 1 - kw) >> 1; wi = wi > WiC - 1 ? WiC - 1 : wi;
            pvs[cc][p] = (kh != 0 || ho + 1 < HoC) && (kw != 0 || wo + 1 < WoC);
            const int sidx =
                __builtin_amdgcn_readfirstlane((b * HoC + 2 * hi) * WoC + 2 * wi);
            bpgr[cc][p] = bp[sidx];                  // uniform -> s_load
            const int hidx = (kh == 0) ? 1 : 0;      // row r+1 = kh0, row r = kh1/2
            pxo[cc][p] = __builtin_amdgcn_readfirstlane(
                             (hidx * 5 + (wi - wi0)) << 10);   // LDS bytes
        }
    }

    // ---- phase 2: per column taps + MFMA + epilogue ----
    #pragma unroll
    for (int cc = 0; cc < 4; ++cc) {
        const int bp_col = bpcol[cc];
        const int q      = (bp_col + 1) & 1;
        const int baseE  = (bp_col + q + 1) >> 1;    // di(kd0) = baseE+m-bpg
        const int baseO  = (bp_col + 1 - q) >> 1;    // di(kd1) = baseO+m-bpg
        int sE[NP], sO[NP];
        #pragma unroll
        for (int p = 0; p < NP; ++p) {               // sentinel folds validity
            const int bpg = bpgr[cc][p] >> 1;
            sE[p] = pvs[cc][p] ? baseE - bpg : -100000;
            sO[p] = pvs[cc][p] ? baseO - bpg : -100000;
        }

        f32x4 accE[2] = {{0.f,0.f,0.f,0.f},{0.f,0.f,0.f,0.f}};
        f32x4 accO[2] = {{0.f,0.f,0.f,0.f},{0.f,0.f,0.f,0.f}};

        #pragma unroll
        for (int g = 0; g < 2; ++g) {
            #pragma unroll
            for (int p = 0; p < NP; ++p) {           // E: kd = 2*half
                const int  di = sE[p] + 16 * g + n - half;
                const bool ok = (unsigned)di < (unsigned)DiC;
                const int  off = ok ? pxo[cc][p] + di * 32 + chalfB : ZOFF;
                short8 a = *(const short8*)((const char*)slabs + off);   // ds_read_b128
                accE[g] = __builtin_amdgcn_mfma_f32_16x16x32_bf16(a, bE[p], accE[g], 0, 0, 0);
            }
            #pragma unroll
            for (int pp = 0; pp < OP; ++pp) {        // O: k-halves = two positions
                const int  PA   = (2 * pp < NP) ? 2 * pp : 0;
                const bool hasB = (2 * pp + 1) < NP;
                const int  PB   = hasB ? (2 * pp + 1) : 0;
                const int  sOs  = half ? (hasB ? sO[PB] : -100000) : sO[PA];
                const int  pxs  = half ? pxo[cc][PB] : pxo[cc][PA];
                const int  di = sOs + 16 * g + n;
                const bool ok = (unsigned)di < (unsigned)DiC;
                const int  off = ok ? pxs + di * 32 + chalfB : ZOFF;
                short8 a = *(const short8*)((const char*)slabs + off);   // ds_read_b128
                accO[g] = __builtin_amdgcn_mfma_f32_16x16x32_bf16(a, bO[pp], accO[g], 0, 0, 0);
            }
        }

        // Wave-private LDS transpose: C/D (row=quad*4+r, col=n) -> [do][f] rows.
        __builtin_amdgcn_wave_barrier();
        if (n < Fc) {
            #pragma unroll
            for (int g = 0; g < 2; ++g) {
                #pragma unroll
                for (int r = 0; r < 4; ++r) {
                    const int m2 = 16 * g + quad * 4 + r;
                    ldsw[(2 * m2 + q) * Fc + n]     = accE[g][r];
                    ldsw[(2 * m2 + 1 - q) * Fc + n] = accO[g][r];
                }
            }
        }
        __builtin_amdgcn_wave_barrier();
        float* outc = out + (size_t)colx[cc] * (DoC * Fc);
        *(float4*)(outc + lane * 8)     = *(const float4*)(ldsw + lane * 8);
        *(float4*)(outc + lane * 8 + 4) = *(const float4*)(ldsw + lane * 8 + 4);
        __builtin_amdgcn_wave_barrier();
    }
}

__global__ __launch_bounds__(256, 8)
void sconv_mfma(const float* __restrict__ img, const int* __restrict__ bp,
                const float* __restrict__ kern, float* __restrict__ out) {
    __shared__ short slabs[NSLAB * SLAB_SHORTS + 8];   // 10 KiB slabs + 16 B zeros
    __shared__ float lds[4 * DoC * Fc];                // 8 KiB transpose scratch
    const int t = threadIdx.x, wv = t >> 6, lane = t & 63;
    const int b = blockIdx.z, r = blockIdx.y;          // ho pair {2r, 2r+1}
    // block covers 8 wo x 2 ho; wave wv = (ho-parity hs, wo-parity p):
    // each wave runs ONE doCols over its 4 same-parity columns wo0 + {0,2,4,6}.
    const int p  = wv & 1, hs = wv >> 1;
    const int wo0 = (blockIdx.x << 3) + p;
    const int wi0 = blockIdx.x << 2;                   // leftmost staged wi
    const int ho  = 2 * r + hs;
    float* ldsw = lds + wv * (DoC * Fc);

    // cooperative slab staging WITH fused f32->bf16 convert: one slab = 512 f32
    // = 64 lanes x (2 float4 loads + pack8 + ds_write_b128). 10 slabs:
    // s in [0,5) -> input row r (hidx0, kh 1/2); s in [5,10) -> row r+1 (hidx1, kh0).
    const int hi0 = r;
    int hi1 = r + 1; if (hi1 > HiC - 1) hi1 = HiC - 1;
    #pragma unroll
    for (int k = 0; k < 3; ++k) {                      // s = wv, wv+4, wv+8 (<=3)
        const int s = wv + 4 * k;
        if (s < NSLAB) {
            const int hi = (s >= 5) ? hi1 : hi0;
            int wi = wi0 + ((s >= 5) ? s - 5 : s); if (wi > WiC - 1) wi = WiC - 1;
            const float* g = img + (((b * HiC + hi) * WiC + wi) << 9) + lane * 8;
            float4 v0 = *(const float4*)g;
            float4 v1 = *(const float4*)(g + 4);
            *(short8*)&slabs[(s << 9) + lane * 8] = pack8(v0, v1);
        }
    }
    if (t < 8) slabs[NSLAB * SLAB_SHORTS + t] = 0;     // 16 B zero block
    __syncthreads();

    if (hs) {
        if (p) doCols<3>(slabs, bp, kern, out, ldsw, b, ho, wo0, wi0, lane);
        else   doCols<2>(slabs, bp, kern, out, ldsw, b, ho, wo0, wi0, lane);
    } else {
        if (p) doCols<1>(slabs, bp, kern, out, ldsw, b, ho, wo0, wi0, lane);
        else   doCols<0>(slabs, bp, kern, out, ldsw, b, ho, wo0, wi0, lane);
    }
}

extern "C" void kernel_launch(void* const* d_in, const int* in_sizes, int n_in,
                              void* d_out, int out_size, void* d_ws, size_t ws_size,
                              hipStream_t stream) {
    const float* images = (const float*)d_in[0];
    const int*   bp     = (const int*)d_in[1];
    const float* kern   = (const float*)d_in[2];
    float* out = (float*)d_out;
    (void)d_ws; (void)ws_size;   // ws untouched (poison fill is unconditional
                                 // anyway — round-2 lesson)

    dim3 grid(WoC / 8, HoC / 2, Bc), block(256);   // 16 x 64 x 2 = 2048 blocks
    hipLaunchKernelGGL(sconv_mfma, grid, block, 0, stream,
                       images, bp, kern, out);
}

// Round 7
// 95.238 us; speedup vs baseline: 1.0007x; 1.0007x over previous
//
#include <hip/hip_runtime.h>

// B=2, Hi=Wi=64, Di=32, C=16, F=8, strides (2,2,2), k=3x3x3, Ho=Wo=128, Do=64.
constexpr int Bc  = 2;
constexpr int HiC = 64, WiC = 64, DiC = 32;
constexpr int Cc  = 16, Fc  = 8;
constexpr int HoC = 128, WoC = 128, DoC = 64;

constexpr int SLAB_SHORTS = DiC * Cc;                  // 512 shorts = 1 KiB slab
constexpr int NSLAB       = 10;                        // 2 hi rows x 5 wi cols
constexpr int ZOFF        = NSLAB * SLAB_SHORTS * 2;   // LDS byte offset of zero block

typedef __attribute__((ext_vector_type(8))) short short8;   // 8 bf16 = A/B frag
typedef __attribute__((ext_vector_type(4))) float f32x4;    // MFMA accumulator

__device__ alignas(16) const float FZERO[8] = {0, 0, 0, 0, 0, 0, 0, 0};

__device__ __forceinline__ unsigned pk2(float x, float y) {   // RNE f32x2 -> bf16x2
    unsigned ux = __float_as_uint(x), uy = __float_as_uint(y);
    ux += ((ux >> 16) & 1u) + 0x7FFFu;
    uy += ((uy >> 16) & 1u) + 0x7FFFu;
    return (ux >> 16) | (uy & 0xFFFF0000u);
}
__device__ __forceinline__ short8 pack8(float4 a, float4 b) {
    union { unsigned u[4]; short8 s; } r;
    r.u[0] = pk2(a.x, a.y); r.u[1] = pk2(a.z, a.w);
    r.u[2] = pk2(b.x, b.y); r.u[3] = pk2(b.z, b.w);
    return r.s;
}

// Wave = 4 same-parity columns of one output row. Per column: out[do,f] over
// (pos,kd,c) packed in MFMA K=32. E rows (bp+do+1 even): per position, k-halves
// = kd0/kd2. O rows (kd=1): two positions per MFMA. A: A[m=lane&15][k=quad*8+j];
// B: B[k][n=lane&15]; C/D: col=lane&15, row=quad*4+reg. (round-7/8 verified)
// Round 15: r5 profile showed VGPR_Count=44 — register starvation forced the
// compiler into read->waitcnt->MFMA serial chains (~24 x 120cy LDS round-trips
// per column = the observed 8x stall gap; occupancy changes r5/r6 were null).
// Fix: batch-load ALL 12 A-frags per column into named registers (independent
// ds_read_b128s, ONE lgkm wait), then MFMA; __launch_bounds__(256,4) gives the
// allocator a 128-VGPR budget (16 waves/CU still).
template<int CLS>
__device__ __forceinline__ void doCols(const short* __restrict__ slabs,
                                       const int*   __restrict__ bp,
                                       const float* __restrict__ kern,
                                       float*       __restrict__ out,
                                       float*       __restrict__ ldsw,
                                       int b, int ho, int wo0, int wi0, int lane) {
    constexpr int NP = (CLS == 0) ? 1 : ((CLS == 3) ? 4 : 2);
    constexpr int OP = (NP + 1) / 2;
    constexpr int KH[4][4] = {{1,0,0,0},{1,1,0,0},{0,2,0,0},{0,0,2,2}};
    constexpr int KW[4][4] = {{1,0,0,0},{0,2,0,0},{1,1,0,0},{0,2,0,2}};

    const int quad = lane >> 4, n = lane & 15;
    const int half = quad >> 1, chalf = quad & 1;   // k-half, channel-half
    const int chalfB = chalf * 16;                  // byte offset within di row

    // ---- B fragments in-register from f32 kern (amortized over 4 columns) ----
    short8 bE[NP], bO[OP];
    #pragma unroll
    for (int p = 0; p < NP; ++p) {
        const int kp = KH[CLS][p] * 3 + KW[CLS][p];
        const float* wp = (n < Fc)
            ? kern + (kp * 3 + 2 * half) * 128 + n * 16 + chalf * 8 : FZERO;
        bE[p] = pack8(*(const float4*)wp, *(const float4*)(wp + 4));
    }
    #pragma unroll
    for (int pp = 0; pp < OP; ++pp) {
        const int  PA   = (2 * pp < NP) ? 2 * pp : 0;
        const bool hasB = (2 * pp + 1) < NP;
        const int  PB   = hasB ? (2 * pp + 1) : 0;
        const int kpa = KH[CLS][PA] * 3 + KW[CLS][PA];
        const int kpb = KH[CLS][PB] * 3 + KW[CLS][PB];
        const int kp  = half ? kpb : kpa;
        const bool v  = (n < Fc) && (!half || hasB);
        const float* wp = v ? kern + (kp * 3 + 1) * 128 + n * 16 + chalf * 8 : FZERO;
        bO[pp] = pack8(*(const float4*)wp, *(const float4*)(wp + 4));
    }

    // ---- phase 1: ALL scalar loads for all 4 columns ----
    int colx[4], bpcol[4], bpgr[4][NP], pxo[4][NP]; bool pvs[4][NP];
    #pragma unroll
    for (int cc = 0; cc < 4; ++cc) {
        const int wo = wo0 + 2 * cc;
        colx[cc]  = __builtin_amdgcn_readfirstlane((b * HoC + ho) * WoC + wo);
        bpcol[cc] = bp[colx[cc]];                    // uniform -> s_load
        #pragma unroll
        for (int p = 0; p < NP; ++p) {
            const int kh = KH[CLS][p], kw = KW[CLS][p];
            int hi = (ho + 1 - kh) >> 1; hi = hi > HiC - 1 ? HiC - 1 : hi;
            int wi = (wo + 1 - kw) >> 1; wi = wi > WiC - 1 ? WiC - 1 : wi;
            pvs[cc][p] = (kh != 0 || ho + 1 < HoC) && (kw != 0 || wo + 1 < WoC);
            const int sidx =
                __builtin_amdgcn_readfirstlane((b * HoC + 2 * hi) * WoC + 2 * wi);
            bpgr[cc][p] = bp[sidx];                  // uniform -> s_load
            const int hidx = (kh == 0) ? 1 : 0;      // row r+1 = kh0, row r = kh1/2
            pxo[cc][p] = __builtin_amdgcn_readfirstlane(
                             (hidx * 5 + (wi - wi0)) << 10);   // LDS bytes
        }
    }

    // ---- phase 2: per column batched tap loads -> MFMA burst -> epilogue ----
    #pragma unroll
    for (int cc = 0; cc < 4; ++cc) {
        const int bp_col = bpcol[cc];
        const int q      = (bp_col + 1) & 1;
        const int baseE  = (bp_col + q + 1) >> 1;    // di(kd0) = baseE+m-bpg
        const int baseO  = (bp_col + 1 - q) >> 1;    // di(kd1) = baseO+m-bpg
        int sE[NP], sO[NP];
        #pragma unroll
        for (int p = 0; p < NP; ++p) {               // sentinel folds validity
            const int bpg = bpgr[cc][p] >> 1;
            sE[p] = pvs[cc][p] ? baseE - bpg : -100000;
            sO[p] = pvs[cc][p] ? baseO - bpg : -100000;
        }

        // batch A-fragment loads: all offsets independent -> back-to-back
        // ds_read_b128 issue, a single lgkm drain before the MFMA burst.
        short8 aE[2][NP], aO[2][OP];
        #pragma unroll
        for (int g = 0; g < 2; ++g) {
            #pragma unroll
            for (int p = 0; p < NP; ++p) {           // E: kd = 2*half
                const int  di = sE[p] + 16 * g + n - half;
                const bool ok = (unsigned)di < (unsigned)DiC;
                const int  off = ok ? pxo[cc][p] + di * 32 + chalfB : ZOFF;
                aE[g][p] = *(const short8*)((const char*)slabs + off);
            }
            #pragma unroll
            for (int pp = 0; pp < OP; ++pp) {        // O: k-halves = two positions
                const int  PA   = (2 * pp < NP) ? 2 * pp : 0;
                const bool hasB = (2 * pp + 1) < NP;
                const int  PB   = hasB ? (2 * pp + 1) : 0;
                const int  sOs  = half ? (hasB ? sO[PB] : -100000) : sO[PA];
                const int  pxs  = half ? pxo[cc][PB] : pxo[cc][PA];
                const int  di = sOs + 16 * g + n;
                const bool ok = (unsigned)di < (unsigned)DiC;
                const int  off = ok ? pxs + di * 32 + chalfB : ZOFF;
                aO[g][pp] = *(const short8*)((const char*)slabs + off);
            }
        }

        f32x4 accE[2] = {{0.f,0.f,0.f,0.f},{0.f,0.f,0.f,0.f}};
        f32x4 accO[2] = {{0.f,0.f,0.f,0.f},{0.f,0.f,0.f,0.f}};
        #pragma unroll
        for (int g = 0; g < 2; ++g) {
            #pragma unroll
            for (int p = 0; p < NP; ++p)
                accE[g] = __builtin_amdgcn_mfma_f32_16x16x32_bf16(aE[g][p], bE[p], accE[g], 0, 0, 0);
            #pragma unroll
            for (int pp = 0; pp < OP; ++pp)
                accO[g] = __builtin_amdgcn_mfma_f32_16x16x32_bf16(aO[g][pp], bO[pp], accO[g], 0, 0, 0);
        }

        // Wave-private LDS transpose: C/D (row=quad*4+r, col=n) -> [do][f] rows.
        __builtin_amdgcn_wave_barrier();
        if (n < Fc) {
            #pragma unroll
            for (int g = 0; g < 2; ++g) {
                #pragma unroll
                for (int r = 0; r < 4; ++r) {
                    const int m2 = 16 * g + quad * 4 + r;
                    ldsw[(2 * m2 + q) * Fc + n]     = accE[g][r];
                    ldsw[(2 * m2 + 1 - q) * Fc + n] = accO[g][r];
                }
            }
        }
        __builtin_amdgcn_wave_barrier();
        float* outc = out + (size_t)colx[cc] * (DoC * Fc);
        *(float4*)(outc + lane * 8)     = *(const float4*)(ldsw + lane * 8);
        *(float4*)(outc + lane * 8 + 4) = *(const float4*)(ldsw + lane * 8 + 4);
        __builtin_amdgcn_wave_barrier();
    }
}

__global__ __launch_bounds__(256, 4)
void sconv_mfma(const float* __restrict__ img, const int* __restrict__ bp,
                const float* __restrict__ kern, float* __restrict__ out) {
    __shared__ short slabs[NSLAB * SLAB_SHORTS + 8];   // 10 KiB slabs + 16 B zeros
    __shared__ float lds[4 * DoC * Fc];                // 8 KiB transpose scratch
    const int t = threadIdx.x, wv = t >> 6, lane = t & 63;
    const int b = blockIdx.z, r = blockIdx.y;          // ho pair {2r, 2r+1}
    // block covers 8 wo x 2 ho; wave wv = (ho-parity hs, wo-parity p):
    // each wave runs ONE doCols over its 4 same-parity columns wo0 + {0,2,4,6}.
    const int p  = wv & 1, hs = wv >> 1;
    const int wo0 = (blockIdx.x << 3) + p;
    const int wi0 = blockIdx.x << 2;                   // leftmost staged wi
    const int ho  = 2 * r + hs;
    float* ldsw = lds + wv * (DoC * Fc);

    // cooperative slab staging WITH fused f32->bf16 convert: one slab = 512 f32
    // = 64 lanes x (2 float4 loads + pack8 + ds_write_b128). 10 slabs:
    // s in [0,5) -> input row r (hidx0, kh 1/2); s in [5,10) -> row r+1 (hidx1, kh0).
    const int hi0 = r;
    int hi1 = r + 1; if (hi1 > HiC - 1) hi1 = HiC - 1;
    #pragma unroll
    for (int k = 0; k < 3; ++k) {                      // s = wv, wv+4, wv+8 (<=3)
        const int s = wv + 4 * k;
        if (s < NSLAB) {
            const int hi = (s >= 5) ? hi1 : hi0;
            int wi = wi0 + ((s >= 5) ? s - 5 : s); if (wi > WiC - 1) wi = WiC - 1;
            const float* g = img + (((b * HiC + hi) * WiC + wi) << 9) + lane * 8;
            float4 v0 = *(const float4*)g;
            float4 v1 = *(const float4*)(g + 4);
            *(short8*)&slabs[(s << 9) + lane * 8] = pack8(v0, v1);
        }
    }
    if (t < 8) slabs[NSLAB * SLAB_SHORTS + t] = 0;     // 16 B zero block
    __syncthreads();

    if (hs) {
        if (p) doCols<3>(slabs, bp, kern, out, ldsw, b, ho, wo0, wi0, lane);
        else   doCols<2>(slabs, bp, kern, out, ldsw, b, ho, wo0, wi0, lane);
    } else {
        if (p) doCols<1>(slabs, bp, kern, out, ldsw, b, ho, wo0, wi0, lane);
        else   doCols<0>(slabs, bp, kern, out, ldsw, b, ho, wo0, wi0, lane);
    }
}

extern "C" void kernel_launch(void* const* d_in, const int* in_sizes, int n_in,
                              void* d_out, int out_size, void* d_ws, size_t ws_size,
                              hipStream_t stream) {
    const float* images = (const float*)d_in[0];
    const int*   bp     = (const int*)d_in[1];
    const float* kern   = (const float*)d_in[2];
    float* out = (float*)d_out;
    (void)d_ws; (void)ws_size;   // ws untouched (poison fill is unconditional
                                 // anyway — round-2 lesson)

    dim3 grid(WoC / 8, HoC / 2, Bc), block(256);   // 16 x 64 x 2 = 2048 blocks
    hipLaunchKernelGGL(sconv_mfma, grid, block, 0, stream,
                       images, bp, kern, out);
}